// Round 5
// baseline (271.957 us; speedup 1.0000x reference)
//
#include <hip/hip_runtime.h>
#include <hip/hip_bf16.h>
#include <stdint.h>

// Problem constants
#define T_TOK 8192   // B*S tokens
#define HID   2048
#define OUTD  2048
#define NE    8
#define RR    16
#define KAUG  2176   // 2048 + NE*RR
#define NH    128    // h columns (NE*RR)

typedef __bf16 bf16x8 __attribute__((ext_vector_type(8)));
typedef float  f32x4  __attribute__((ext_vector_type(4)));

#define AS1(p) ((__attribute__((address_space(1))) void*)(p))
#define AS3(p) ((__attribute__((address_space(3))) void*)(p))

__device__ inline unsigned short f2bf(float f) {
  unsigned int u = __builtin_bit_cast(unsigned int, f);
  unsigned int r = (u + 0x7fffu + ((u >> 16) & 1u)) >> 16;   // RNE
  return (unsigned short)r;
}

__device__ inline ushort4 f2bf4(float4 v) {
  ushort4 u;
  u.x = f2bf(v.x); u.y = f2bf(v.y); u.z = f2bf(v.z); u.w = f2bf(v.w);
  return u;
}

// ---- fused: x -> bf16 Xa[:,0:2048]  +  exact fp64 router -> wte[t][8] ----
// one wave per token; 2048 blocks x 256 threads  (verbatim round-3, proven)
__global__ __launch_bounds__(256) void k_xrl(const float* __restrict__ x,
                                             const float* __restrict__ gw,
                                             unsigned short* __restrict__ Xa,
                                             float* __restrict__ wte) {
  int w = threadIdx.x >> 6, lane = threadIdx.x & 63;
  int t = blockIdx.x * 4 + w;
  const float* xt = x + (size_t)t * HID;
  unsigned short* xo = Xa + (size_t)t * KAUG;
  double acc[8] = {0, 0, 0, 0, 0, 0, 0, 0};
#pragma unroll
  for (int i = 0; i < 8; ++i) {
    int k = (i * 64 + lane) * 4;
    float4 xv = *(const float4*)(xt + k);
    *(ushort4*)(xo + k) = f2bf4(xv);
#pragma unroll
    for (int e = 0; e < 8; ++e) {
      float4 gv = *(const float4*)(gw + (size_t)e * HID + k);
      acc[e] += (double)xv.x * gv.x + (double)xv.y * gv.y +
                (double)xv.z * gv.z + (double)xv.w * gv.w;
    }
  }
#pragma unroll
  for (int off = 32; off >= 1; off >>= 1)
#pragma unroll
    for (int e = 0; e < 8; ++e)
      acc[e] += __shfl_down(acc[e], off, 64);
  if (lane == 0) {
    int e0 = 0; double l0 = acc[0];
#pragma unroll
    for (int e = 1; e < 8; ++e) if (acc[e] > l0) { l0 = acc[e]; e0 = e; }
    int e1 = -1; double l1 = -1e300;
#pragma unroll
    for (int e = 0; e < 8; ++e) if (e != e0 && acc[e] > l1) { l1 = acc[e]; e1 = e; }
    double w0 = 16.0 / (1.0 + exp(l1 - l0));
    float o[8] = {0.f, 0.f, 0.f, 0.f, 0.f, 0.f, 0.f, 0.f};
    o[e0] = (float)w0;
    o[e1] = (float)(16.0 - w0);
    float4* p = (float4*)(wte + (size_t)t * 8);
    p[0] = make_float4(o[0], o[1], o[2], o[3]);
    p[1] = make_float4(o[4], o[5], o[6], o[7]);
  }
}

// ---- fused weight converts; per-thread bodies verbatim round-3 ----
// blocks [0,4096)    : W -> Wa[:,0:2048]        (round-3 k_cvt_w)
// blocks [4096,4352) : B -> Wa[:,2048+e*16+r]   (round-3 k_cvt_b)
// blocks [4352,4608) : A -> Ag                  (round-3 k_cvt_a)
__global__ void k_wba(const float* __restrict__ W, const float* __restrict__ Bw,
                      const float* __restrict__ A,
                      unsigned short* __restrict__ Wa, unsigned short* __restrict__ Ag) {
  int b = blockIdx.x;
  if (b < 4096) {
    int tid = b * 256 + threadIdx.x;
    int row = tid >> 9, c = (tid & 511) << 2;
    float4 v = *(const float4*)(W + (size_t)row * HID + c);
    *(ushort4*)(Wa + (size_t)row * KAUG + c) = f2bf4(v);
  } else if (b < 4352) {
    int tid = (b - 4096) * 256 + threadIdx.x;
    int o = tid >> 5, j = (tid & 31) << 2;
    int e = j >> 4, r = j & 15;
    float4 v = *(const float4*)(Bw + (size_t)e * OUTD * RR + (size_t)o * RR + r);
    *(ushort4*)(Wa + (size_t)o * KAUG + 2048 + j) = f2bf4(v);
  } else {
    int tid = (b - 4352) * 256 + threadIdx.x;
    float4 v = *(const float4*)(A + (size_t)tid * 4);
    *(ushort4*)(Ag + (size_t)tid * 4) = f2bf4(v);
  }
}

// ---- fused h-GEMM + router scale: writes bf16 aug cols of Xa directly ----
// (verbatim round-3, proven)
__global__ __launch_bounds__(256) void k_ha(const unsigned short* __restrict__ Xa,
                                            const unsigned short* __restrict__ Ag,
                                            const float* __restrict__ wte,
                                            unsigned short* __restrict__ XaW) {
  __shared__ unsigned short Xs[32 * 64];
  __shared__ unsigned short As[128 * 64];
  int tm = blockIdx.x * 32;
  int w = threadIdx.x >> 6, lane = threadIdx.x & 63;
  int lrow = lane >> 3;
  int lcol_s = (lane & 7) << 3;                       // LDS dest (forced contiguous)
  int lcol_g = ((lane & 7) ^ (lrow & 7)) << 3;        // swizzled global source

  const unsigned short* gX = Xa + (size_t)(tm + w * 8 + lrow) * KAUG + lcol_g;
  const unsigned short* gA = Ag + (size_t)(w * 32 + lrow) * HID + lcol_g;
  unsigned short* sX = Xs + (w * 8 + lrow) * 64 + lcol_s;
  unsigned short* sA = As + (w * 32 + lrow) * 64 + lcol_s;

  f32x4 acc[4] = {};
  for (int kt = 0; kt < HID; kt += 64) {
    __builtin_amdgcn_global_load_lds(AS1(gX), AS3(sX), 16, 0, 0);
#pragma unroll
    for (int i = 0; i < 4; ++i)
      __builtin_amdgcn_global_load_lds(AS1(gA + (size_t)i * 8 * HID), AS3(sA + i * 8 * 64), 16, 0, 0);
    __syncthreads();
#pragma unroll
    for (int ks = 0; ks < 2; ++ks) {
      int kch = ks * 4 + (lane >> 4);
      int ko = ((kch ^ (lane & 7)) << 3);             // swizzled read offset
      bf16x8 a = *(const bf16x8*)(Xs + ((w >> 1) * 16 + (lane & 15)) * 64 + ko);
#pragma unroll
      for (int fn = 0; fn < 4; ++fn) {
        bf16x8 bv = *(const bf16x8*)(As + ((w & 1) * 64 + fn * 16 + (lane & 15)) * 64 + ko);
        acc[fn] = __builtin_amdgcn_mfma_f32_16x16x32_bf16(a, bv, acc[fn], 0, 0, 0);
      }
    }
    __syncthreads();
    gX += 64; gA += 64;
  }
  int q = lane >> 4;
#pragma unroll
  for (int fn = 0; fn < 4; ++fn) {
    int col = (w & 1) * 64 + fn * 16 + (lane & 15);
    int e = col >> 4;
#pragma unroll
    for (int r = 0; r < 4; ++r) {
      int t = tm + (w >> 1) * 16 + q * 4 + r;
      float we = wte[(size_t)t * 8 + e];
      XaW[(size_t)t * KAUG + 2048 + col] = f2bf(we * acc[fn][r]);
    }
  }
}

// ---- main GEMM: out[t][o] = sum_{k<2176} Xa[t][k]*Wa[o][k] ----
// m97 structure + XOR-swizzled LDS + XCD-aware block swizzle (verbatim round-3)
__global__ __launch_bounds__(256) void k_gemm(const unsigned short* __restrict__ Xa,
                                              const unsigned short* __restrict__ Wa,
                                              float* __restrict__ out) {
  __shared__ unsigned short As[128 * 64];
  __shared__ unsigned short Bs[128 * 64];
  int lid = blockIdx.x;                 // grid = 1024 linear
  int xcd = lid & 7, s = lid >> 3;
  int bm = (xcd * 8 + (s & 7)) * 128;   // 0..63
  int bn = (s >> 3) * 128;              // 0..15
  int w = threadIdx.x >> 6, lane = threadIdx.x & 63;
  int wm = (w >> 1) * 64, wn = (w & 1) * 64;
  int lrow = lane >> 3;
  int lcol_s = (lane & 7) << 3;
  int lcol_g = ((lane & 7) ^ (lrow & 7)) << 3;

  const unsigned short* gA = Xa + (size_t)(bm + w * 32 + lrow) * KAUG + lcol_g;
  const unsigned short* gB = Wa + (size_t)(bn + w * 32 + lrow) * KAUG + lcol_g;
  unsigned short* sA = As + (w * 32 + lrow) * 64 + lcol_s;
  unsigned short* sB = Bs + (w * 32 + lrow) * 64 + lcol_s;

  f32x4 acc[4][4] = {};
  for (int kt = 0; kt < KAUG; kt += 64) {
#pragma unroll
    for (int i = 0; i < 4; ++i) {
      __builtin_amdgcn_global_load_lds(AS1(gA + (size_t)i * 8 * KAUG), AS3(sA + i * 8 * 64), 16, 0, 0);
      __builtin_amdgcn_global_load_lds(AS1(gB + (size_t)i * 8 * KAUG), AS3(sB + i * 8 * 64), 16, 0, 0);
    }
    __syncthreads();
#pragma unroll
    for (int ks = 0; ks < 2; ++ks) {
      int kch = ks * 4 + (lane >> 4);
      int ko = ((kch ^ (lane & 7)) << 3);             // swizzled read offset
      bf16x8 a[4], b[4];
#pragma unroll
      for (int f = 0; f < 4; ++f) a[f] = *(const bf16x8*)(As + (wm + f * 16 + (lane & 15)) * 64 + ko);
#pragma unroll
      for (int f = 0; f < 4; ++f) b[f] = *(const bf16x8*)(Bs + (wn + f * 16 + (lane & 15)) * 64 + ko);
#pragma unroll
      for (int fm = 0; fm < 4; ++fm)
#pragma unroll
        for (int fn = 0; fn < 4; ++fn)
          acc[fm][fn] = __builtin_amdgcn_mfma_f32_16x16x32_bf16(a[fm], b[fn], acc[fm][fn], 0, 0, 0);
    }
    __syncthreads();
    gA += 64; gB += 64;
  }
#pragma unroll
  for (int fm = 0; fm < 4; ++fm) {
    int row = bm + wm + fm * 16 + ((lane >> 4) << 2);
#pragma unroll
    for (int r = 0; r < 4; ++r) {
      float* orow = out + (size_t)(row + r) * OUTD + bn + wn + (lane & 15);
#pragma unroll
      for (int fn = 0; fn < 4; ++fn) orow[fn * 16] = acc[fm][fn][r];
    }
  }
}

extern "C" void kernel_launch(void* const* d_in, const int* in_sizes, int n_in,
                              void* d_out, int out_size, void* d_ws, size_t ws_size,
                              hipStream_t stream) {
  const float* x  = (const float*)d_in[0];
  const float* W  = (const float*)d_in[1];
  const float* gw = (const float*)d_in[2];
  const float* A  = (const float*)d_in[3];
  const float* B  = (const float*)d_in[4];
  float* out = (float*)d_out;

  char* ws = (char*)d_ws;
  unsigned short* Xa  = (unsigned short*)(ws);                  // 8192*2176*2 = 35,651,584
  unsigned short* Wa  = (unsigned short*)(ws + 35651584);       // 2048*2176*2 =  8,912,896
  unsigned short* Ag  = (unsigned short*)(ws + 44564480);       //  128*2048*2 =    524,288
  float*          wte = (float*)        (ws + 45088768);        // 8192*8*4    =    262,144
  // total 45,350,912 bytes

  k_xrl <<<2048, 256, 0, stream>>>(x, gw, Xa, wte);
  k_wba <<<4608, 256, 0, stream>>>(W, B, A, Wa, Ag);
  k_ha  <<<256, 256, 0, stream>>>(Xa, Ag, wte, Xa);
  k_gemm<<<1024, 256, 0, stream>>>(Xa, Wa, out);
}

// Round 6
// 245.910 us; speedup vs baseline: 1.1059x; 1.1059x over previous
//
#include <hip/hip_runtime.h>
#include <hip/hip_bf16.h>
#include <stdint.h>

// Problem constants
#define T_TOK 8192   // B*S tokens
#define HID   2048
#define OUTD  2048
#define NE    8
#define RR    16
#define KAUG  2176   // 2048 + NE*RR
#define NH    128    // h columns (NE*RR)

typedef __bf16 bf16x8 __attribute__((ext_vector_type(8)));
typedef float  f32x4  __attribute__((ext_vector_type(4)));

#define AS1(p) ((__attribute__((address_space(1))) void*)(p))
#define AS3(p) ((__attribute__((address_space(3))) void*)(p))

__device__ inline unsigned short f2bf(float f) {
  unsigned int u = __builtin_bit_cast(unsigned int, f);
  unsigned int r = (u + 0x7fffu + ((u >> 16) & 1u)) >> 16;   // RNE
  return (unsigned short)r;
}

__device__ inline ushort4 f2bf4(float4 v) {
  ushort4 u;
  u.x = f2bf(v.x); u.y = f2bf(v.y); u.z = f2bf(v.z); u.w = f2bf(v.w);
  return u;
}

// ---- fused: x -> bf16 Xa[:,0:2048]  +  exact fp64 router -> wte[t][8] ----
// one wave per token; 2048 blocks x 256 threads  (verbatim round-3, proven)
__global__ __launch_bounds__(256) void k_xrl(const float* __restrict__ x,
                                             const float* __restrict__ gw,
                                             unsigned short* __restrict__ Xa,
                                             float* __restrict__ wte) {
  int w = threadIdx.x >> 6, lane = threadIdx.x & 63;
  int t = blockIdx.x * 4 + w;
  const float* xt = x + (size_t)t * HID;
  unsigned short* xo = Xa + (size_t)t * KAUG;
  double acc[8] = {0, 0, 0, 0, 0, 0, 0, 0};
#pragma unroll
  for (int i = 0; i < 8; ++i) {
    int k = (i * 64 + lane) * 4;
    float4 xv = *(const float4*)(xt + k);
    *(ushort4*)(xo + k) = f2bf4(xv);
#pragma unroll
    for (int e = 0; e < 8; ++e) {
      float4 gv = *(const float4*)(gw + (size_t)e * HID + k);
      acc[e] += (double)xv.x * gv.x + (double)xv.y * gv.y +
                (double)xv.z * gv.z + (double)xv.w * gv.w;
    }
  }
#pragma unroll
  for (int off = 32; off >= 1; off >>= 1)
#pragma unroll
    for (int e = 0; e < 8; ++e)
      acc[e] += __shfl_down(acc[e], off, 64);
  if (lane == 0) {
    int e0 = 0; double l0 = acc[0];
#pragma unroll
    for (int e = 1; e < 8; ++e) if (acc[e] > l0) { l0 = acc[e]; e0 = e; }
    int e1 = -1; double l1 = -1e300;
#pragma unroll
    for (int e = 0; e < 8; ++e) if (e != e0 && acc[e] > l1) { l1 = acc[e]; e1 = e; }
    double w0 = 16.0 / (1.0 + exp(l1 - l0));
    float o[8] = {0.f, 0.f, 0.f, 0.f, 0.f, 0.f, 0.f, 0.f};
    o[e0] = (float)w0;
    o[e1] = (float)(16.0 - w0);
    float4* p = (float4*)(wte + (size_t)t * 8);
    p[0] = make_float4(o[0], o[1], o[2], o[3]);
    p[1] = make_float4(o[4], o[5], o[6], o[7]);
  }
}

// ---- fused weight converts; per-thread bodies verbatim round-3 ----
__global__ void k_wba(const float* __restrict__ W, const float* __restrict__ Bw,
                      const float* __restrict__ A,
                      unsigned short* __restrict__ Wa, unsigned short* __restrict__ Ag) {
  int b = blockIdx.x;
  if (b < 4096) {
    int tid = b * 256 + threadIdx.x;
    int row = tid >> 9, c = (tid & 511) << 2;
    float4 v = *(const float4*)(W + (size_t)row * HID + c);
    *(ushort4*)(Wa + (size_t)row * KAUG + c) = f2bf4(v);
  } else if (b < 4352) {
    int tid = (b - 4096) * 256 + threadIdx.x;
    int o = tid >> 5, j = (tid & 31) << 2;
    int e = j >> 4, r = j & 15;
    float4 v = *(const float4*)(Bw + (size_t)e * OUTD * RR + (size_t)o * RR + r);
    *(ushort4*)(Wa + (size_t)o * KAUG + 2048 + j) = f2bf4(v);
  } else {
    int tid = (b - 4352) * 256 + threadIdx.x;
    float4 v = *(const float4*)(A + (size_t)tid * 4);
    *(ushort4*)(Ag + (size_t)tid * 4) = f2bf4(v);
  }
}

// ---- fused h-GEMM + router scale: writes bf16 aug cols of Xa directly ----
// 512 blocks (2/CU for latency overlap): block = 32 tokens x 64 cols.
// Same arithmetic as round-3 version, col-space split across block pairs.
__global__ __launch_bounds__(256) void k_ha(const unsigned short* __restrict__ Xa,
                                            const unsigned short* __restrict__ Ag,
                                            const float* __restrict__ wte,
                                            unsigned short* __restrict__ XaW) {
  __shared__ unsigned short Xs[32 * 64];
  __shared__ unsigned short As[64 * 64];
  int tm = (blockIdx.x >> 1) * 32;
  int ch = (blockIdx.x & 1) * 64;       // column half of the 128 h-cols
  int w = threadIdx.x >> 6, lane = threadIdx.x & 63;
  int lrow = lane >> 3;
  int lcol_s = (lane & 7) << 3;                       // LDS dest (forced contiguous)
  int lcol_g = ((lane & 7) ^ (lrow & 7)) << 3;        // swizzled global source

  const unsigned short* gX = Xa + (size_t)(tm + w * 8 + lrow) * KAUG + lcol_g;
  const unsigned short* gA = Ag + (size_t)(ch + w * 16 + lrow) * HID + lcol_g;
  unsigned short* sX = Xs + (w * 8 + lrow) * 64 + lcol_s;
  unsigned short* sA = As + (w * 16 + lrow) * 64 + lcol_s;

  f32x4 acc[2] = {};
  for (int kt = 0; kt < HID; kt += 64) {
    __builtin_amdgcn_global_load_lds(AS1(gX), AS3(sX), 16, 0, 0);
#pragma unroll
    for (int i = 0; i < 2; ++i)
      __builtin_amdgcn_global_load_lds(AS1(gA + (size_t)i * 8 * HID), AS3(sA + i * 8 * 64), 16, 0, 0);
    __syncthreads();
#pragma unroll
    for (int ks = 0; ks < 2; ++ks) {
      int kch = ks * 4 + (lane >> 4);
      int ko = ((kch ^ (lane & 7)) << 3);             // swizzled read offset
      bf16x8 a = *(const bf16x8*)(Xs + ((w >> 1) * 16 + (lane & 15)) * 64 + ko);
#pragma unroll
      for (int fn = 0; fn < 2; ++fn) {
        bf16x8 bv = *(const bf16x8*)(As + ((w & 1) * 32 + fn * 16 + (lane & 15)) * 64 + ko);
        acc[fn] = __builtin_amdgcn_mfma_f32_16x16x32_bf16(a, bv, acc[fn], 0, 0, 0);
      }
    }
    __syncthreads();
    gX += 64; gA += 64;
  }
  int q = lane >> 4;
#pragma unroll
  for (int fn = 0; fn < 2; ++fn) {
    int col = ch + (w & 1) * 32 + fn * 16 + (lane & 15);
    int e = col >> 4;
#pragma unroll
    for (int r = 0; r < 4; ++r) {
      int t = tm + (w >> 1) * 16 + q * 4 + r;
      float we = wte[(size_t)t * 8 + e];
      XaW[(size_t)t * KAUG + 2048 + col] = f2bf(we * acc[fn][r]);
    }
  }
}

// ---- main GEMM: out[t][o] = sum_{k<2176} Xa[t][k]*Wa[o][k] ----
// m97 structure + XOR-swizzled LDS + XCD swizzle.
// __launch_bounds__(256,4): cap regs at 128/thread (64 VGPR + 64 AGPR acc)
// so all 4 blocks/CU (grid 1024 = 4x256) are co-resident -> no 3+1 tail.
__global__ __launch_bounds__(256, 4) void k_gemm(const unsigned short* __restrict__ Xa,
                                                 const unsigned short* __restrict__ Wa,
                                                 float* __restrict__ out) {
  __shared__ unsigned short As[128 * 64];
  __shared__ unsigned short Bs[128 * 64];
  int lid = blockIdx.x;                 // grid = 1024 linear
  int xcd = lid & 7, s = lid >> 3;
  int bm = (xcd * 8 + (s & 7)) * 128;   // 0..63
  int bn = (s >> 3) * 128;              // 0..15
  int w = threadIdx.x >> 6, lane = threadIdx.x & 63;
  int wm = (w >> 1) * 64, wn = (w & 1) * 64;
  int lrow = lane >> 3;
  int lcol_s = (lane & 7) << 3;
  int lcol_g = ((lane & 7) ^ (lrow & 7)) << 3;

  const unsigned short* gA = Xa + (size_t)(bm + w * 32 + lrow) * KAUG + lcol_g;
  const unsigned short* gB = Wa + (size_t)(bn + w * 32 + lrow) * KAUG + lcol_g;
  unsigned short* sA = As + (w * 32 + lrow) * 64 + lcol_s;
  unsigned short* sB = Bs + (w * 32 + lrow) * 64 + lcol_s;

  f32x4 acc[4][4] = {};
  for (int kt = 0; kt < KAUG; kt += 64) {
#pragma unroll
    for (int i = 0; i < 4; ++i) {
      __builtin_amdgcn_global_load_lds(AS1(gA + (size_t)i * 8 * KAUG), AS3(sA + i * 8 * 64), 16, 0, 0);
      __builtin_amdgcn_global_load_lds(AS1(gB + (size_t)i * 8 * KAUG), AS3(sB + i * 8 * 64), 16, 0, 0);
    }
    __syncthreads();
#pragma unroll
    for (int ks = 0; ks < 2; ++ks) {
      int kch = ks * 4 + (lane >> 4);
      int ko = ((kch ^ (lane & 7)) << 3);             // swizzled read offset
      bf16x8 a[4], b[4];
#pragma unroll
      for (int f = 0; f < 4; ++f) a[f] = *(const bf16x8*)(As + (wm + f * 16 + (lane & 15)) * 64 + ko);
#pragma unroll
      for (int f = 0; f < 4; ++f) b[f] = *(const bf16x8*)(Bs + (wn + f * 16 + (lane & 15)) * 64 + ko);
#pragma unroll
      for (int fm = 0; fm < 4; ++fm)
#pragma unroll
        for (int fn = 0; fn < 4; ++fn)
          acc[fm][fn] = __builtin_amdgcn_mfma_f32_16x16x32_bf16(a[fm], b[fn], acc[fm][fn], 0, 0, 0);
    }
    __syncthreads();
    gA += 64; gB += 64;
  }
#pragma unroll
  for (int fm = 0; fm < 4; ++fm) {
    int row = bm + wm + fm * 16 + ((lane >> 4) << 2);
#pragma unroll
    for (int r = 0; r < 4; ++r) {
      float* orow = out + (size_t)(row + r) * OUTD + bn + wn + (lane & 15);
#pragma unroll
      for (int fn = 0; fn < 4; ++fn) orow[fn * 16] = acc[fm][fn][r];
    }
  }
}

extern "C" void kernel_launch(void* const* d_in, const int* in_sizes, int n_in,
                              void* d_out, int out_size, void* d_ws, size_t ws_size,
                              hipStream_t stream) {
  const float* x  = (const float*)d_in[0];
  const float* W  = (const float*)d_in[1];
  const float* gw = (const float*)d_in[2];
  const float* A  = (const float*)d_in[3];
  const float* B  = (const float*)d_in[4];
  float* out = (float*)d_out;

  char* ws = (char*)d_ws;
  unsigned short* Xa  = (unsigned short*)(ws);                  // 8192*2176*2 = 35,651,584
  unsigned short* Wa  = (unsigned short*)(ws + 35651584);       // 2048*2176*2 =  8,912,896
  unsigned short* Ag  = (unsigned short*)(ws + 44564480);       //  128*2048*2 =    524,288
  float*          wte = (float*)        (ws + 45088768);        // 8192*8*4    =    262,144
  // total 45,350,912 bytes

  k_xrl <<<2048, 256, 0, stream>>>(x, gw, Xa, wte);
  k_wba <<<4608, 256, 0, stream>>>(W, B, A, Wa, Ag);
  k_ha  <<<512, 256, 0, stream>>>(Xa, Ag, wte, Xa);
  k_gemm<<<1024, 256, 0, stream>>>(Xa, Wa, out);
}